// Round 2
// baseline (850.844 us; speedup 1.0000x reference)
//
#include <hip/hip_runtime.h>
#include <hip/hip_bf16.h>
#include <math.h>

#define N 8192
#define D 256
#define EPSF 1e-6f

typedef __attribute__((ext_vector_type(8))) short short8v;
typedef __attribute__((ext_vector_type(4))) float f32x4;

__device__ __forceinline__ unsigned short f2bf(float x) {
    __hip_bfloat16 h = __float2bfloat16(x);
    return *(unsigned short*)&h;
}
__device__ __forceinline__ float bf2f(unsigned short u) {
    __hip_bfloat16 h = *(__hip_bfloat16*)&u;
    return __bfloat162float(h);
}

// ---------------- Kernel 1: Q row sums (Sq), zero wsum ----------------
__global__ __launch_bounds__(256) void qrowsum_kernel(const float* __restrict__ Q,
                                                      float* __restrict__ Sq,
                                                      float* __restrict__ wsum) {
    int row = blockIdx.x;
    const float4* q4 = (const float4*)(Q + (size_t)row * N);
    float s = 0.f;
    for (int k = threadIdx.x; k < N / 4; k += 256) {
        float4 v = q4[k];
        s += v.x + v.y + v.z + v.w;
    }
    __shared__ float red[4];
    for (int off = 32; off > 0; off >>= 1) s += __shfl_down(s, off, 64);
    if ((threadIdx.x & 63) == 0) red[threadIdx.x >> 6] = s;
    __syncthreads();
    if (threadIdx.x == 0) {
        Sq[row] = red[0] + red[1] + red[2] + red[3];
        wsum[row] = 0.f;
    }
}

// ---------------- Kernel 2: split z -> Bh, Bl (bf16 hi/lo) ----------------
__global__ __launch_bounds__(256) void split_kernel(const float* __restrict__ x,
                                                    unsigned short* __restrict__ hi,
                                                    unsigned short* __restrict__ lo) {
    int i = (blockIdx.x * 256 + threadIdx.x) * 4;
    float4 v = *(const float4*)&x[i];
    ushort4 h, l;
    float a;
    a = v.x; h.x = f2bf(a); l.x = f2bf(a - bf2f(h.x));
    a = v.y; h.y = f2bf(a); l.y = f2bf(a - bf2f(h.y));
    a = v.z; h.z = f2bf(a); l.z = f2bf(a - bf2f(h.z));
    a = v.w; h.w = f2bf(a); l.w = f2bf(a - bf2f(h.w));
    *(ushort4*)&hi[i] = h;
    *(ushort4*)&lo[i] = l;
}

// ---------------- Kernel 3: zW = z @ W, split to Ah, Al ----------------
__global__ __launch_bounds__(256) void zw_kernel(const float* __restrict__ z,
                                                 const float* __restrict__ W,
                                                 unsigned short* __restrict__ Ah,
                                                 unsigned short* __restrict__ Al) {
    __shared__ float zs[32 * D];  // 32 rows of z, 32 KB
    int rowBase = blockIdx.x * 32;
    const float4* zg = (const float4*)(z + (size_t)rowBase * D);
    float4* zs4 = (float4*)zs;
    for (int i = threadIdx.x; i < 32 * D / 4; i += 256) zs4[i] = zg[i];
    __syncthreads();

    float acc[32];
#pragma unroll
    for (int r = 0; r < 32; ++r) acc[r] = 0.f;
    int col = threadIdx.x;
    for (int kb = 0; kb < D; kb += 4) {
        float w0 = W[(size_t)(kb + 0) * D + col];
        float w1 = W[(size_t)(kb + 1) * D + col];
        float w2 = W[(size_t)(kb + 2) * D + col];
        float w3 = W[(size_t)(kb + 3) * D + col];
#pragma unroll
        for (int r = 0; r < 32; ++r) {
            float4 zv = *(const float4*)&zs[r * D + kb];
            acc[r] = fmaf(zv.x, w0, acc[r]);
            acc[r] = fmaf(zv.y, w1, acc[r]);
            acc[r] = fmaf(zv.z, w2, acc[r]);
            acc[r] = fmaf(zv.w, w3, acc[r]);
        }
    }
#pragma unroll
    for (int r = 0; r < 32; ++r) {
        float a = acc[r];
        unsigned short h = f2bf(a);
        unsigned short l = f2bf(a - bf2f(h));
        Ah[(size_t)(rowBase + r) * D + col] = h;
        Al[(size_t)(rowBase + r) * D + col] = l;
    }
}

// ---------------- Kernel 4: sim = zW @ z^T via split-bf16 MFMA, fused epilogue ----------------
// 128x128 tile per block, 4 waves, each wave 64x64 (4x4 frags of 16x16x32).
// LDS tiles [128][32] bf16 for Ah,Al,Bh,Bl with 16B-slot XOR swizzle: slot' = slot ^ ((row>>1)&3).
__global__ __launch_bounds__(256, 2) void sim_mfma_kernel(
    const unsigned short* __restrict__ Ah, const unsigned short* __restrict__ Al,
    const unsigned short* __restrict__ Bh, const unsigned short* __restrict__ Bl,
    const float* __restrict__ beta, const float* __restrict__ Q,
    const float* __restrict__ Sq, float* __restrict__ out, float* __restrict__ wsum) {
    __shared__ unsigned short lds[4][128][32];  // 32 KB

    // XCD-aware swizzle (4096 blocks, 8 XCDs, bijective since 4096%8==0)
    int bid = blockIdx.x;
    int swz = (bid & 7) * 512 + (bid >> 3);
    int bx = swz & 63;
    int by = swz >> 6;
    int rowBase = by * 128;
    int colBase = bx * 128;

    int t = threadIdx.x;
    int lane = t & 63;
    int w = t >> 6;
    int wr = w >> 1, wc = w & 1;  // 2x2 wave grid, 64x64 per wave
    int fr = lane & 15;           // frag row/col index
    int fg = lane >> 4;           // k-slot group

    f32x4 acc[4][4];
#pragma unroll
    for (int m = 0; m < 4; ++m)
#pragma unroll
        for (int n = 0; n < 4; ++n) acc[m][n] = (f32x4){0.f, 0.f, 0.f, 0.f};

    // staging map: thread covers slots {s0, s0+1} of row t>>1 in each tile
    const int srow = t >> 1;
    const int s0 = (t & 1) * 2;

    const unsigned short* gsrc[4];
    gsrc[0] = Ah + (size_t)(rowBase + srow) * D;
    gsrc[1] = Al + (size_t)(rowBase + srow) * D;
    gsrc[2] = Bh + (size_t)(colBase + srow) * D;
    gsrc[3] = Bl + (size_t)(colBase + srow) * D;

    float4 pre[8];

    auto loadstep = [&](int kt) {
#pragma unroll
        for (int tile = 0; tile < 4; ++tile) {
            pre[tile * 2 + 0] = *(const float4*)(gsrc[tile] + kt + s0 * 8);
            pre[tile * 2 + 1] = *(const float4*)(gsrc[tile] + kt + s0 * 8 + 8);
        }
    };
    auto writestep = [&]() {
        int swrow = (srow >> 1) & 3;
#pragma unroll
        for (int tile = 0; tile < 4; ++tile) {
            *(float4*)&lds[tile][srow][((s0 + 0) ^ swrow) * 8] = pre[tile * 2 + 0];
            *(float4*)&lds[tile][srow][((s0 + 1) ^ swrow) * 8] = pre[tile * 2 + 1];
        }
    };

    loadstep(0);
    for (int kt = 0; kt < D; kt += 32) {
        __syncthreads();  // previous compute done reading LDS
        writestep();
        __syncthreads();
        if (kt + 32 < D) loadstep(kt + 32);  // prefetch under MFMA phase

        short8v ahf[4], alf[4], bhf[4], blf[4];
#pragma unroll
        for (int m = 0; m < 4; ++m) {
            int row = wr * 64 + m * 16 + fr;
            int sl = fg ^ ((row >> 1) & 3);
            ahf[m] = *(const short8v*)&lds[0][row][sl * 8];
            alf[m] = *(const short8v*)&lds[1][row][sl * 8];
        }
#pragma unroll
        for (int n = 0; n < 4; ++n) {
            int row = wc * 64 + n * 16 + fr;
            int sl = fg ^ ((row >> 1) & 3);
            bhf[n] = *(const short8v*)&lds[2][row][sl * 8];
            blf[n] = *(const short8v*)&lds[3][row][sl * 8];
        }
#pragma unroll
        for (int m = 0; m < 4; ++m)
#pragma unroll
            for (int n = 0; n < 4; ++n) {
                acc[m][n] = __builtin_amdgcn_mfma_f32_16x16x32_bf16(ahf[m], bhf[n], acc[m][n], 0, 0, 0);
                acc[m][n] = __builtin_amdgcn_mfma_f32_16x16x32_bf16(ahf[m], blf[n], acc[m][n], 0, 0, 0);
                acc[m][n] = __builtin_amdgcn_mfma_f32_16x16x32_bf16(alf[m], bhf[n], acc[m][n], 0, 0, 0);
            }
    }

    // epilogue: v = sqrt(relu(sim-beta)+eps) * (0.5 + Q*0.5/Sq); write v; rowsum atomics
    // D layout: col = fr (lane&15), row = fg*4 + reg
#pragma unroll
    for (int m = 0; m < 4; ++m) {
#pragma unroll
        for (int reg = 0; reg < 4; ++reg) {
            int i = rowBase + wr * 64 + m * 16 + fg * 4 + reg;
            float bi = beta[i];
            float inv2s = 0.5f / Sq[i];
            float rs = 0.f;
#pragma unroll
            for (int n = 0; n < 4; ++n) {
                int jg = colBase + wc * 64 + n * 16 + fr;
                float s = acc[m][n][reg];
                float x = fmaxf(s - bi, 0.f) + EPSF;
                float q = Q[(size_t)i * N + jg];
                float v = sqrtf(x) * fmaf(q, inv2s, 0.5f);
                out[(size_t)i * N + jg] = v;
                rs += v;
            }
            rs += __shfl_xor(rs, 1, 64);
            rs += __shfl_xor(rs, 2, 64);
            rs += __shfl_xor(rs, 4, 64);
            rs += __shfl_xor(rs, 8, 64);
            if (fr == 0) atomicAdd(&wsum[i], rs);
        }
    }
}

// ---------------- Kernel 5: row-normalize ----------------
__global__ __launch_bounds__(256) void norm_kernel(float* __restrict__ out,
                                                   const float* __restrict__ wsum) {
    int row = blockIdx.x;
    float inv = 1.0f / wsum[row];
    float4* o4 = (float4*)(out + (size_t)row * N);
    for (int k = threadIdx.x; k < N / 4; k += 256) {
        float4 v = o4[k];
        v.x *= inv;
        v.y *= inv;
        v.z *= inv;
        v.w *= inv;
        o4[k] = v;
    }
}

extern "C" void kernel_launch(void* const* d_in, const int* in_sizes, int n_in,
                              void* d_out, int out_size, void* d_ws, size_t ws_size,
                              hipStream_t stream) {
    const float* z = (const float*)d_in[0];
    const float* W = (const float*)d_in[1];
    const float* beta = (const float*)d_in[2];
    const float* Q = (const float*)d_in[3];
    float* out = (float*)d_out;

    float* Sq = (float*)d_ws;                       // N f32
    float* wsum = Sq + N;                           // N f32
    unsigned short* Ah = (unsigned short*)(wsum + N);  // N*D bf16 each
    unsigned short* Al = Ah + (size_t)N * D;
    unsigned short* Bh = Al + (size_t)N * D;
    unsigned short* Bl = Bh + (size_t)N * D;

    qrowsum_kernel<<<N, 256, 0, stream>>>(Q, Sq, wsum);
    split_kernel<<<(N * D / 4) / 256, 256, 0, stream>>>(z, Bh, Bl);
    zw_kernel<<<N / 32, 256, 0, stream>>>(z, W, Ah, Al);
    sim_mfma_kernel<<<4096, 256, 0, stream>>>(Ah, Al, Bh, Bl, beta, Q, Sq, out, wsum);
    norm_kernel<<<N, 256, 0, stream>>>(out, wsum);
}

// Round 3
// 826.136 us; speedup vs baseline: 1.0299x; 1.0299x over previous
//
#include <hip/hip_runtime.h>
#include <hip/hip_bf16.h>
#include <math.h>

#define N 8192
#define D 256
#define EPSF 1e-6f

typedef __attribute__((ext_vector_type(8))) short short8v;
typedef __attribute__((ext_vector_type(4))) float f32x4;

__device__ __forceinline__ unsigned short f2bf(float x) {
    __hip_bfloat16 h = __float2bfloat16(x);
    return *(unsigned short*)&h;
}
__device__ __forceinline__ float bf2f(unsigned short u) {
    __hip_bfloat16 h = *(__hip_bfloat16*)&u;
    return __bfloat162float(h);
}

// ---------------- Kernel 1: Q row sums (Sq), zero wsum ----------------
__global__ __launch_bounds__(256) void qrowsum_kernel(const float* __restrict__ Q,
                                                      float* __restrict__ Sq,
                                                      float* __restrict__ wsum) {
    int row = blockIdx.x;
    const float4* q4 = (const float4*)(Q + (size_t)row * N);
    float s = 0.f;
    for (int k = threadIdx.x; k < N / 4; k += 256) {
        float4 v = q4[k];
        s += v.x + v.y + v.z + v.w;
    }
    __shared__ float red[4];
    for (int off = 32; off > 0; off >>= 1) s += __shfl_down(s, off, 64);
    if ((threadIdx.x & 63) == 0) red[threadIdx.x >> 6] = s;
    __syncthreads();
    if (threadIdx.x == 0) {
        Sq[row] = red[0] + red[1] + red[2] + red[3];
        wsum[row] = 0.f;
    }
}

// ---------------- Kernel 2: split z -> Bh, Bl (bf16 hi/lo) ----------------
__global__ __launch_bounds__(256) void split_kernel(const float* __restrict__ x,
                                                    unsigned short* __restrict__ hi,
                                                    unsigned short* __restrict__ lo) {
    int i = (blockIdx.x * 256 + threadIdx.x) * 4;
    float4 v = *(const float4*)&x[i];
    ushort4 h, l;
    float a;
    a = v.x; h.x = f2bf(a); l.x = f2bf(a - bf2f(h.x));
    a = v.y; h.y = f2bf(a); l.y = f2bf(a - bf2f(h.y));
    a = v.z; h.z = f2bf(a); l.z = f2bf(a - bf2f(h.z));
    a = v.w; h.w = f2bf(a); l.w = f2bf(a - bf2f(h.w));
    *(ushort4*)&hi[i] = h;
    *(ushort4*)&lo[i] = l;
}

// ---------------- Kernel 3: zW = z @ W, split to Ah, Al ----------------
__global__ __launch_bounds__(256) void zw_kernel(const float* __restrict__ z,
                                                 const float* __restrict__ W,
                                                 unsigned short* __restrict__ Ah,
                                                 unsigned short* __restrict__ Al) {
    __shared__ float zs[32 * D];  // 32 rows of z, 32 KB
    int rowBase = blockIdx.x * 32;
    const float4* zg = (const float4*)(z + (size_t)rowBase * D);
    float4* zs4 = (float4*)zs;
    for (int i = threadIdx.x; i < 32 * D / 4; i += 256) zs4[i] = zg[i];
    __syncthreads();

    float acc[32];
#pragma unroll
    for (int r = 0; r < 32; ++r) acc[r] = 0.f;
    int col = threadIdx.x;
    for (int kb = 0; kb < D; kb += 4) {
        float w0 = W[(size_t)(kb + 0) * D + col];
        float w1 = W[(size_t)(kb + 1) * D + col];
        float w2 = W[(size_t)(kb + 2) * D + col];
        float w3 = W[(size_t)(kb + 3) * D + col];
#pragma unroll
        for (int r = 0; r < 32; ++r) {
            float4 zv = *(const float4*)&zs[r * D + kb];
            acc[r] = fmaf(zv.x, w0, acc[r]);
            acc[r] = fmaf(zv.y, w1, acc[r]);
            acc[r] = fmaf(zv.z, w2, acc[r]);
            acc[r] = fmaf(zv.w, w3, acc[r]);
        }
    }
#pragma unroll
    for (int r = 0; r < 32; ++r) {
        float a = acc[r];
        unsigned short h = f2bf(a);
        unsigned short l = f2bf(a - bf2f(h));
        Ah[(size_t)(rowBase + r) * D + col] = h;
        Al[(size_t)(rowBase + r) * D + col] = l;
    }
}

// ---------------- Kernel 4: sim = zW @ z^T via split-bf16 MFMA, fused epilogue ----------------
// 128x128 tile per block, 4 waves, each wave 64x64 (4x4 frags of 16x16x32).
// LDS tiles [128][32] bf16 for Ah,Al,Bh,Bl with 16B-slot XOR swizzle (0 conflicts, verified r2).
// Epilogue repacks acc through per-wave LDS scratch so Q loads / out stores are float4.
__global__ __launch_bounds__(256, 4) void sim_mfma_kernel(
    const unsigned short* __restrict__ Ah, const unsigned short* __restrict__ Al,
    const unsigned short* __restrict__ Bh, const unsigned short* __restrict__ Bl,
    const float* __restrict__ beta, const float* __restrict__ Q,
    const float* __restrict__ Sq, float* __restrict__ out, float* __restrict__ wsum) {
    __shared__ unsigned short lds[4][128][32];  // 32 KB staging, reused as epilogue scratch

    // XCD-aware banded mapping, column-major within each XCD's 8-tile-row band:
    // concurrent working set per XCD ~= 8 A-panels + ~20 B-panels ~= 3.5 MB < 4 MB L2.
    int bid = blockIdx.x;          // 0..4095
    int xcd = bid & 7;
    int idx = bid >> 3;            // 0..511
    int bx = idx >> 3;             // col tile 0..63 (slow)
    int rowIn = idx & 7;           // row within band (fast)
    int by = xcd * 8 + rowIn;      // row tile 0..63
    int rowBase = by * 128;
    int colBase = bx * 128;

    int t = threadIdx.x;
    int lane = t & 63;
    int w = t >> 6;
    int wr = w >> 1, wc = w & 1;  // 2x2 wave grid, 64x64 per wave
    int fr = lane & 15;           // frag row/col index
    int fg = lane >> 4;           // k-slot group

    f32x4 acc[4][4];
#pragma unroll
    for (int m = 0; m < 4; ++m)
#pragma unroll
        for (int n = 0; n < 4; ++n) acc[m][n] = (f32x4){0.f, 0.f, 0.f, 0.f};

    // staging map: thread covers slots {s0, s0+1} of row t>>1 in each tile
    const int srow = t >> 1;
    const int s0 = (t & 1) * 2;

    const unsigned short* gsrc[4];
    gsrc[0] = Ah + (size_t)(rowBase + srow) * D;
    gsrc[1] = Al + (size_t)(rowBase + srow) * D;
    gsrc[2] = Bh + (size_t)(colBase + srow) * D;
    gsrc[3] = Bl + (size_t)(colBase + srow) * D;

    float4 pre[8];

    auto loadstep = [&](int kt) {
#pragma unroll
        for (int tile = 0; tile < 4; ++tile) {
            pre[tile * 2 + 0] = *(const float4*)(gsrc[tile] + kt + s0 * 8);
            pre[tile * 2 + 1] = *(const float4*)(gsrc[tile] + kt + s0 * 8 + 8);
        }
    };
    auto writestep = [&]() {
        int swrow = (srow >> 1) & 3;
#pragma unroll
        for (int tile = 0; tile < 4; ++tile) {
            *(float4*)&lds[tile][srow][((s0 + 0) ^ swrow) * 8] = pre[tile * 2 + 0];
            *(float4*)&lds[tile][srow][((s0 + 1) ^ swrow) * 8] = pre[tile * 2 + 1];
        }
    };

    loadstep(0);
    for (int kt = 0; kt < D; kt += 32) {
        __syncthreads();  // previous compute done reading LDS
        writestep();
        __syncthreads();
        if (kt + 32 < D) loadstep(kt + 32);  // prefetch under MFMA phase

        short8v bhf[4], blf[4];
#pragma unroll
        for (int n = 0; n < 4; ++n) {
            int row = wc * 64 + n * 16 + fr;
            int sl = fg ^ ((row >> 1) & 3);
            bhf[n] = *(const short8v*)&lds[2][row][sl * 8];
            blf[n] = *(const short8v*)&lds[3][row][sl * 8];
        }
#pragma unroll
        for (int m = 0; m < 4; ++m) {
            int row = wr * 64 + m * 16 + fr;
            int sl = fg ^ ((row >> 1) & 3);
            short8v ahf = *(const short8v*)&lds[0][row][sl * 8];
            short8v alf = *(const short8v*)&lds[1][row][sl * 8];
#pragma unroll
            for (int n = 0; n < 4; ++n) {
                acc[m][n] = __builtin_amdgcn_mfma_f32_16x16x32_bf16(ahf, bhf[n], acc[m][n], 0, 0, 0);
                acc[m][n] = __builtin_amdgcn_mfma_f32_16x16x32_bf16(ahf, blf[n], acc[m][n], 0, 0, 0);
                acc[m][n] = __builtin_amdgcn_mfma_f32_16x16x32_bf16(alf, bhf[n], acc[m][n], 0, 0, 0);
            }
        }
    }

    // ---- epilogue: repack 16x64 row-groups through LDS so memory ops are float4 ----
    __syncthreads();  // all waves done reading staging LDS; reuse it as scratch
    float* scratch = (float*)lds + w * (16 * 68);  // per-wave 16 rows x 68 floats (4352 B)

#pragma unroll
    for (int m = 0; m < 4; ++m) {
        // scatter acc (D layout: row_local = fg*4+reg, col_local = n*16+fr) into scratch
#pragma unroll
        for (int n = 0; n < 4; ++n)
#pragma unroll
            for (int reg = 0; reg < 4; ++reg)
                scratch[(fg * 4 + reg) * 68 + n * 16 + fr] = acc[m][n][reg];

        // gather: lane owns row (sub*4 + lane>>4), 16 consecutive cols at (lane&15)*4
#pragma unroll
        for (int sub = 0; sub < 4; ++sub) {
            int rloc = sub * 4 + fg;
            int i = rowBase + wr * 64 + m * 16 + rloc;
            int col = colBase + wc * 64 + fr * 4;
            float4 sv = *(const float4*)&scratch[rloc * 68 + fr * 4];
            float4 qv = *(const float4*)&Q[(size_t)i * N + col];
            float bi = beta[i];
            float inv2s = 0.5f / Sq[i];
            float4 vv;
            vv.x = sqrtf(fmaxf(sv.x - bi, 0.f) + EPSF) * fmaf(qv.x, inv2s, 0.5f);
            vv.y = sqrtf(fmaxf(sv.y - bi, 0.f) + EPSF) * fmaf(qv.y, inv2s, 0.5f);
            vv.z = sqrtf(fmaxf(sv.z - bi, 0.f) + EPSF) * fmaf(qv.z, inv2s, 0.5f);
            vv.w = sqrtf(fmaxf(sv.w - bi, 0.f) + EPSF) * fmaf(qv.w, inv2s, 0.5f);
            *(float4*)&out[(size_t)i * N + col] = vv;
            float rs = vv.x + vv.y + vv.z + vv.w;
            rs += __shfl_xor(rs, 1, 64);
            rs += __shfl_xor(rs, 2, 64);
            rs += __shfl_xor(rs, 4, 64);
            rs += __shfl_xor(rs, 8, 64);
            if (fr == 0) atomicAdd(&wsum[i], rs);
        }
        __syncthreads();  // scratch WAR across waves sharing the LDS buffer? per-wave regions are
                          // disjoint, but acc->scratch of m+1 must not pass reads of m (same wave,
                          // DS ops are in-order) — barrier kept cheap & safe for cross-wave timing.
    }
}

// ---------------- Kernel 5: row-normalize ----------------
__global__ __launch_bounds__(256) void norm_kernel(float* __restrict__ out,
                                                   const float* __restrict__ wsum) {
    int row = blockIdx.x;
    float inv = 1.0f / wsum[row];
    float4* o4 = (float4*)(out + (size_t)row * N);
    for (int k = threadIdx.x; k < N / 4; k += 256) {
        float4 v = o4[k];
        v.x *= inv;
        v.y *= inv;
        v.z *= inv;
        v.w *= inv;
        o4[k] = v;
    }
}

extern "C" void kernel_launch(void* const* d_in, const int* in_sizes, int n_in,
                              void* d_out, int out_size, void* d_ws, size_t ws_size,
                              hipStream_t stream) {
    const float* z = (const float*)d_in[0];
    const float* W = (const float*)d_in[1];
    const float* beta = (const float*)d_in[2];
    const float* Q = (const float*)d_in[3];
    float* out = (float*)d_out;

    float* Sq = (float*)d_ws;                          // N f32
    float* wsum = Sq + N;                              // N f32
    unsigned short* Ah = (unsigned short*)(wsum + N);  // N*D bf16 each
    unsigned short* Al = Ah + (size_t)N * D;
    unsigned short* Bh = Al + (size_t)N * D;
    unsigned short* Bl = Bh + (size_t)N * D;

    qrowsum_kernel<<<N, 256, 0, stream>>>(Q, Sq, wsum);
    split_kernel<<<(N * D / 4) / 256, 256, 0, stream>>>(z, Bh, Bl);
    zw_kernel<<<N / 32, 256, 0, stream>>>(z, W, Ah, Al);
    sim_mfma_kernel<<<4096, 256, 0, stream>>>(Ah, Al, Bh, Bl, beta, Q, Sq, out, wsum);
    norm_kernel<<<N, 256, 0, stream>>>(out, wsum);
}